// Round 1
// baseline (277.578 us; speedup 1.0000x reference)
//
#include <hip/hip_runtime.h>

// Problem constants (from setup_inputs): B=16, H=W=64, Cin=512, K=dim=64
#define NB 16
#define HW 4096
#define CIN 512
#define KCL 64
#define BP 128                  // pixels per block
#define NCHUNK (HW / BP)        // 32 blocks per batch
#define KCSTEP 32               // c-channels per staged chunk
#define NKC (CIN / KCSTEP)      // 16
#define XS_STRIDE 136           // multiple of 4 -> aligned ds_read_b128
#define FS_STRIDE 68            // multiple of 4 -> aligned ds_read_b128

// smem (floats), two aliased phases:
//   phase1: xs[32][136] @0 (4352), ws[32][64] @4352 (2048)
//   phase2: fs[128][68] @0 (8704), ss @8704 (8704), sums4[4][64] @17408 (256)
#define SMEM_FLOATS 17664

__global__ __launch_bounds__(256, 2) void vlad_main(
    const float* __restrict__ x, const float* __restrict__ Wm,
    const float* __restrict__ bv, float* __restrict__ A_g,
    float* __restrict__ sumS_g)
{
    __shared__ float smem[SMEM_FLOATS];
    float* xs = smem;             // [32][XS_STRIDE]
    float* ws = smem + 4352;      // [32][64]
    float* fs = smem;             // [128][FS_STRIDE]
    float* ss = smem + 8704;      // [128][FS_STRIDE]
    float* sums4 = smem + 17408;  // [4][64]

    const int t = threadIdx.x;
    const int b = blockIdx.x / NCHUNK;
    const int chunk = blockIdx.x % NCHUNK;
    const int pixel_base = b * HW + chunk * BP;

    const int kg = t & 15;   // k = kg + 16*j, j=0..3 (strided to dodge LDS bank aliasing)
    const int pg = t >> 4;   // pixels p = pg*8 + i, i=0..7

    float acc[8][4];
#pragma unroll
    for (int i = 0; i < 8; ++i)
#pragma unroll
        for (int j = 0; j < 4; ++j) acc[i][j] = 0.f;

    for (int kc = 0; kc < NKC; ++kc) {
        const int cbase = kc * KCSTEP;
        __syncthreads();
        // stage x tile transposed: xs[c][p]
#pragma unroll
        for (int rep = 0; rep < 4; ++rep) {
            const int idx = rep * 256 + t;
            const int p = idx >> 3;
            const int c4 = idx & 7;
            const float4 v = *(const float4*)(x + (size_t)(pixel_base + p) * CIN + cbase + c4 * 4);
            float* d = xs + (c4 * 4) * XS_STRIDE + p;
            d[0] = v.x;
            d[XS_STRIDE] = v.y;
            d[2 * XS_STRIDE] = v.z;
            d[3 * XS_STRIDE] = v.w;
        }
        // stage W tile: ws[c][k]
#pragma unroll
        for (int rep = 0; rep < 2; ++rep) {
            const int idx = rep * 256 + t;
            const int c = idx >> 4;
            const int k4 = idx & 15;
            *(float4*)(ws + c * 64 + k4 * 4) =
                *(const float4*)(Wm + (size_t)(cbase + c) * KCL + k4 * 4);
        }
        __syncthreads();
#pragma unroll
        for (int c = 0; c < KCSTEP; ++c) {
            const float* xr = xs + c * XS_STRIDE + pg * 8;
            const float4 p0 = *(const float4*)(xr);
            const float4 p1 = *(const float4*)(xr + 4);
            const float wv0 = ws[c * 64 + kg];
            const float wv1 = ws[c * 64 + kg + 16];
            const float wv2 = ws[c * 64 + kg + 32];
            const float wv3 = ws[c * 64 + kg + 48];
            const float pv[8] = {p0.x, p0.y, p0.z, p0.w, p1.x, p1.y, p1.z, p1.w};
#pragma unroll
            for (int i = 0; i < 8; ++i) {
                acc[i][0] = fmaf(pv[i], wv0, acc[i][0]);
                acc[i][1] = fmaf(pv[i], wv1, acc[i][1]);
                acc[i][2] = fmaf(pv[i], wv2, acc[i][2]);
                acc[i][3] = fmaf(pv[i], wv3, acc[i][3]);
            }
        }
    }

    // + bias
    float bj[4];
#pragma unroll
    for (int j = 0; j < 4; ++j) bj[j] = bv[kg + 16 * j];
#pragma unroll
    for (int i = 0; i < 8; ++i)
#pragma unroll
        for (int j = 0; j < 4; ++j) acc[i][j] += bj[j];

    __syncthreads();  // xs/ws dead; fs/ss alias them

    // softmax per pixel row: row lives in one 16-lane group (kg = lane bits 0..3)
#pragma unroll
    for (int i = 0; i < 8; ++i) {
        float m = fmaxf(fmaxf(acc[i][0], acc[i][1]), fmaxf(acc[i][2], acc[i][3]));
        m = fmaxf(m, __shfl_xor(m, 1));
        m = fmaxf(m, __shfl_xor(m, 2));
        m = fmaxf(m, __shfl_xor(m, 4));
        m = fmaxf(m, __shfl_xor(m, 8));
        const float e0 = __expf(acc[i][0] - m);
        const float e1 = __expf(acc[i][1] - m);
        const float e2 = __expf(acc[i][2] - m);
        const float e3 = __expf(acc[i][3] - m);
        float l = e0 + e1 + e2 + e3;
        l += __shfl_xor(l, 1);
        l += __shfl_xor(l, 2);
        l += __shfl_xor(l, 4);
        l += __shfl_xor(l, 8);
        const float rl = 1.0f / l;
        const int p = pg * 8 + i;
        float* fr = fs + p * FS_STRIDE;
        float* sr = ss + p * FS_STRIDE;
        fr[kg]      = acc[i][0];
        fr[kg + 16] = acc[i][1];
        fr[kg + 32] = acc[i][2];
        fr[kg + 48] = acc[i][3];
        sr[kg]      = e0 * rl;
        sr[kg + 16] = e1 * rl;
        sr[kg + 32] = e2 * rl;
        sr[kg + 48] = e3 * rl;
    }
    __syncthreads();

    // per-cluster soft-assignment mass: sumS[k] = sum_p s[p][k]
    {
        const int col = t & 63;
        const int pr = (t >> 6) * 32;
        float sp = 0.f;
#pragma unroll 8
        for (int p = 0; p < 32; ++p) sp += ss[(pr + p) * FS_STRIDE + col];
        sums4[(t >> 6) * 64 + col] = sp;
    }

    // partial A[d][k] = sum_p f[p][d] * s[p][k]  (64x64, inner 128)
    const int td = t & 15;
    const int tk = t >> 4;
    float Aacc[4][4];
#pragma unroll
    for (int di = 0; di < 4; ++di)
#pragma unroll
        for (int kj = 0; kj < 4; ++kj) Aacc[di][kj] = 0.f;

#pragma unroll 4
    for (int p = 0; p < BP; ++p) {
        const float4 fd = *(const float4*)(fs + p * FS_STRIDE + td * 4);
        const float4 sk = *(const float4*)(ss + p * FS_STRIDE + tk * 4);
        const float fdv[4] = {fd.x, fd.y, fd.z, fd.w};
        const float skv[4] = {sk.x, sk.y, sk.z, sk.w};
#pragma unroll
        for (int di = 0; di < 4; ++di)
#pragma unroll
            for (int kj = 0; kj < 4; ++kj)
                Aacc[di][kj] = fmaf(fdv[di], skv[kj], Aacc[di][kj]);
    }
    __syncthreads();  // sums4 complete

    float* Ab = A_g + b * (KCL * KCL);
#pragma unroll
    for (int di = 0; di < 4; ++di)
#pragma unroll
        for (int kj = 0; kj < 4; ++kj)
            atomicAdd(Ab + (td * 4 + di) * KCL + tk * 4 + kj, Aacc[di][kj]);

    if (t < 64) {
        const float s4 = sums4[t] + sums4[64 + t] + sums4[128 + t] + sums4[192 + t];
        atomicAdd(sumS_g + b * KCL + t, s4);
    }
}

__global__ __launch_bounds__(256) void vlad_finalize(
    const float* __restrict__ A_g, const float* __restrict__ sumS_g,
    const float* __restrict__ Cm, float* __restrict__ out)
{
    __shared__ float red[4];
    const int b = blockIdx.x;
    const int t = threadIdx.x;
    const int k = t >> 2;   // cluster
    const int dg = t & 3;   // 16-element d chunk
    const float sS = sumS_g[b * 64 + k];
    float v[16];
    float ssq = 0.f;
#pragma unroll
    for (int i = 0; i < 16; ++i) {
        const int d = dg * 16 + i;
        const float val = A_g[((size_t)b * 64 + d) * 64 + k] + Cm[d * 64 + k] * sS;
        v[i] = val;
        ssq += val * val;
    }
    // per-cluster sum of squares lives in 4-lane groups (aligned)
    ssq += __shfl_xor(ssq, 1);
    ssq += __shfl_xor(ssq, 2);
    const float rn = rsqrtf(fmaxf(ssq, 1e-12f));
    float gpart = 0.f;
#pragma unroll
    for (int i = 0; i < 16; ++i) {
        v[i] *= rn;
        gpart += v[i] * v[i];
    }
#pragma unroll
    for (int m = 1; m < 64; m <<= 1) gpart += __shfl_xor(gpart, m);
    if ((t & 63) == 0) red[t >> 6] = gpart;
    __syncthreads();
    const float gsq = red[0] + red[1] + red[2] + red[3];
    const float gr = rsqrtf(fmaxf(gsq, 1e-12f));
    float* o = out + (size_t)b * 4096 + k * 64 + dg * 16;
#pragma unroll
    for (int i = 0; i < 16; ++i) o[i] = v[i] * gr;
}

__global__ void vlad_zero(float* p, int n)
{
    const int i = blockIdx.x * blockDim.x + threadIdx.x;
    if (i < n) p[i] = 0.f;
}

extern "C" void kernel_launch(void* const* d_in, const int* in_sizes, int n_in,
                              void* d_out, int out_size, void* d_ws, size_t ws_size,
                              hipStream_t stream)
{
    const float* x  = (const float*)d_in[0];  // [16,64,64,512]
    const float* Wm = (const float*)d_in[1];  // [512,64]
    const float* bv = (const float*)d_in[2];  // [64]
    const float* Cm = (const float*)d_in[3];  // [64,64] (leading 1s dropped)
    float* A_g = (float*)d_ws;                // 16*4096 floats
    float* sumS_g = A_g + NB * KCL * KCL;     // 16*64 floats
    const int nz = NB * KCL * KCL + NB * KCL;

    vlad_zero<<<(nz + 255) / 256, 256, 0, stream>>>(A_g, nz);
    vlad_main<<<NB * NCHUNK, 256, 0, stream>>>(x, Wm, bv, A_g, sumS_g);
    vlad_finalize<<<NB, 256, 0, stream>>>(A_g, sumS_g, Cm, (float*)d_out);
}

// Round 3
// 228.299 us; speedup vs baseline: 1.2159x; 1.2159x over previous
//
#include <hip/hip_runtime.h>

// B=16, H=W=64, Cin=512, K=dim=64
#define NB 16
#define HW 4096
#define CIN 512
#define KCL 64
#define BP 128                 // pixels per block
#define NCHUNK (HW / BP)       // 32
#define WT_STRIDE 520          // bf16 elems; 520*2=1040 B -> uniform LDS bank load
#define FS_STRIDE 68

// smem phases (aliased):
//   phase1: ushort wt[64][520]                  = 66560 B
//   phase2: float fs[128][68] (34816) + ss (34816) + sums4[256] (1024) = 70656 B
#define SMEM_FLOATS 17664      // 70656 B

typedef short s16x8 __attribute__((ext_vector_type(8)));
typedef float f32x4 __attribute__((ext_vector_type(4)));

__device__ __forceinline__ unsigned short f2bf(float f) {
    unsigned u = __builtin_bit_cast(unsigned, f);
    u += 0x7fffu + ((u >> 16) & 1u);   // round-to-nearest-even
    return (unsigned short)(u >> 16);
}

// prep: zero accumulators + convert/transpose W -> Wt_g bf16 [64][512]
__global__ void vlad_prep(const float* __restrict__ Wm, float* __restrict__ A_g,
                          unsigned short* __restrict__ Wt_g)
{
    const int i = blockIdx.x * 256 + threadIdx.x;
    if (i < NB * KCL * KCL + NB * KCL) A_g[i] = 0.f;   // A_g and sumS contiguous
    if (i < CIN * KCL) {
        const int k = i >> 6;
        const int n = i & 63;
        Wt_g[n * 512 + k] = f2bf(Wm[i]);
    }
}

__global__ __launch_bounds__(256, 2) void vlad_main(
    const float* __restrict__ x, const unsigned short* __restrict__ Wt_g,
    const float* __restrict__ bv, float* __restrict__ A_g,
    float* __restrict__ sumS_g)
{
    __shared__ float smem_f[SMEM_FLOATS];
    unsigned short* wt = (unsigned short*)smem_f;   // [64][520]
    float* fs = smem_f;                              // [128][68]
    float* ss = smem_f + BP * FS_STRIDE;             // +8704
    float* sums4 = smem_f + 2 * BP * FS_STRIDE;      // +17408

    const int t = threadIdx.x;
    const int b = blockIdx.x >> 5;
    const int chunk = blockIdx.x & 31;
    const int pb = b * HW + chunk * BP;

    // ---- stage Wt (bf16, padded stride) ----
    {
        const int n = t >> 2;
        const int kc = (t & 3) * 128;
        const unsigned short* src = Wt_g + n * 512 + kc;
        unsigned short* dst = wt + n * WT_STRIDE + kc;
#pragma unroll
        for (int i = 0; i < 16; ++i)
            *(float4*)(dst + i * 8) = *(const float4*)(src + i * 8);
    }
    __syncthreads();

    const int wid = t >> 6;
    const int lane = t & 63;
    const int col = lane & 15;     // MFMA: A-row / B-col / D-col
    const int g = lane >> 4;       // k-group
    const int wpix = pb + wid * 32;   // wave owns 32 pixels (2 M-tiles)

    f32x4 acc[2][4];
#pragma unroll
    for (int mt = 0; mt < 2; ++mt)
#pragma unroll
        for (int nt = 0; nt < 4; ++nt) acc[mt][nt] = (f32x4){0.f, 0.f, 0.f, 0.f};

    const float* xr = x + (size_t)(wpix + col) * CIN + g * 8;
    const unsigned short* wb = wt + col * WT_STRIDE + g * 8;

#pragma unroll
    for (int kk = 0; kk < 16; ++kk) {
        const int k0 = kk * 32;
        s16x8 a[2];
#pragma unroll
        for (int mt = 0; mt < 2; ++mt) {
            const float4 u0 = *(const float4*)(xr + mt * (16 * CIN) + k0);
            const float4 u1 = *(const float4*)(xr + mt * (16 * CIN) + k0 + 4);
            a[mt][0] = (short)f2bf(u0.x); a[mt][1] = (short)f2bf(u0.y);
            a[mt][2] = (short)f2bf(u0.z); a[mt][3] = (short)f2bf(u0.w);
            a[mt][4] = (short)f2bf(u1.x); a[mt][5] = (short)f2bf(u1.y);
            a[mt][6] = (short)f2bf(u1.z); a[mt][7] = (short)f2bf(u1.w);
        }
#pragma unroll
        for (int nt = 0; nt < 4; ++nt) {
            const s16x8 bfr = *(const s16x8*)(wb + nt * (16 * WT_STRIDE) + k0);
            acc[0][nt] = __builtin_amdgcn_mfma_f32_16x16x32_bf16(a[0], bfr, acc[0][nt], 0, 0, 0);
            acc[1][nt] = __builtin_amdgcn_mfma_f32_16x16x32_bf16(a[1], bfr, acc[1][nt], 0, 0, 0);
        }
    }
    __syncthreads();   // wt dead; fs/ss alias it

    // ---- bias + softmax from accumulators; write F,S to LDS ----
    float bj[4];
#pragma unroll
    for (int nt = 0; nt < 4; ++nt) bj[nt] = bv[nt * 16 + col];

#pragma unroll
    for (int mt = 0; mt < 2; ++mt)
#pragma unroll
        for (int r = 0; r < 4; ++r) {
            float v0 = acc[mt][0][r] + bj[0];
            float v1 = acc[mt][1][r] + bj[1];
            float v2 = acc[mt][2][r] + bj[2];
            float v3 = acc[mt][3][r] + bj[3];
            float m = fmaxf(fmaxf(v0, v1), fmaxf(v2, v3));
            m = fmaxf(m, __shfl_xor(m, 1));
            m = fmaxf(m, __shfl_xor(m, 2));
            m = fmaxf(m, __shfl_xor(m, 4));
            m = fmaxf(m, __shfl_xor(m, 8));
            const float e0 = __expf(v0 - m);
            const float e1 = __expf(v1 - m);
            const float e2 = __expf(v2 - m);
            const float e3 = __expf(v3 - m);
            float lsum = e0 + e1 + e2 + e3;
            lsum += __shfl_xor(lsum, 1);
            lsum += __shfl_xor(lsum, 2);
            lsum += __shfl_xor(lsum, 4);
            lsum += __shfl_xor(lsum, 8);
            const float rl = 1.0f / lsum;
            const int p = wid * 32 + mt * 16 + g * 4 + r;   // D-row = (lane>>4)*4+reg
            float* fr = fs + p * FS_STRIDE + col;
            fr[0] = v0; fr[16] = v1; fr[32] = v2; fr[48] = v3;
            float* sr = ss + p * FS_STRIDE + col;
            sr[0] = e0 * rl; sr[16] = e1 * rl; sr[32] = e2 * rl; sr[48] = e3 * rl;
        }
    __syncthreads();

    // ---- per-cluster mass sumS[k] ----
    {
        const int c64 = t & 63;
        const int pr = (t >> 6) * 32;
        float sp = 0.f;
#pragma unroll 8
        for (int p = 0; p < 32; ++p) sp += ss[(pr + p) * FS_STRIDE + c64];
        sums4[(t >> 6) * 64 + c64] = sp;
    }

    // ---- partial A[d][k] = sum_p F[p][d]*S[p][k] (f32, exact) ----
    const int td = t & 15;
    const int tk = t >> 4;
    float Aacc[4][4];
#pragma unroll
    for (int di = 0; di < 4; ++di)
#pragma unroll
        for (int kj = 0; kj < 4; ++kj) Aacc[di][kj] = 0.f;

#pragma unroll 4
    for (int p = 0; p < BP; ++p) {
        const float4 fd = *(const float4*)(fs + p * FS_STRIDE + td * 4);
        const float4 sk = *(const float4*)(ss + p * FS_STRIDE + tk * 4);
        const float fdv[4] = {fd.x, fd.y, fd.z, fd.w};
        const float skv[4] = {sk.x, sk.y, sk.z, sk.w};
#pragma unroll
        for (int di = 0; di < 4; ++di)
#pragma unroll
            for (int kj = 0; kj < 4; ++kj)
                Aacc[di][kj] = fmaf(fdv[di], skv[kj], Aacc[di][kj]);
    }
    __syncthreads();   // sums4 complete

    float* Ab = A_g + b * (KCL * KCL);
#pragma unroll
    for (int di = 0; di < 4; ++di)
#pragma unroll
        for (int kj = 0; kj < 4; ++kj)
            atomicAdd(Ab + (td * 4 + di) * KCL + tk * 4 + kj, Aacc[di][kj]);

    if (t < 64) {
        const float s4 = sums4[t] + sums4[64 + t] + sums4[128 + t] + sums4[192 + t];
        atomicAdd(sumS_g + b * KCL + t, s4);
    }
}

__global__ __launch_bounds__(256) void vlad_finalize(
    const float* __restrict__ A_g, const float* __restrict__ sumS_g,
    const float* __restrict__ Cm, float* __restrict__ out)
{
    __shared__ float red[4];
    const int b = blockIdx.x;
    const int t = threadIdx.x;
    const int k = t >> 2;
    const int dg = t & 3;
    const float sS = sumS_g[b * 64 + k];
    float v[16];
    float ssq = 0.f;
#pragma unroll
    for (int i = 0; i < 16; ++i) {
        const int d = dg * 16 + i;
        const float val = A_g[((size_t)b * 64 + d) * 64 + k] + Cm[d * 64 + k] * sS;
        v[i] = val;
        ssq += val * val;
    }
    ssq += __shfl_xor(ssq, 1);
    ssq += __shfl_xor(ssq, 2);
    const float rn = rsqrtf(fmaxf(ssq, 1e-12f));
    float gpart = 0.f;
#pragma unroll
    for (int i = 0; i < 16; ++i) {
        v[i] *= rn;
        gpart += v[i] * v[i];
    }
#pragma unroll
    for (int m = 1; m < 64; m <<= 1) gpart += __shfl_xor(gpart, m);
    if ((t & 63) == 0) red[t >> 6] = gpart;
    __syncthreads();
    const float gsq = red[0] + red[1] + red[2] + red[3];
    const float gr = rsqrtf(fmaxf(gsq, 1e-12f));
    float* o = out + (size_t)b * 4096 + k * 64 + dg * 16;
#pragma unroll
    for (int i = 0; i < 16; ++i) o[i] = v[i] * gr;
}

extern "C" void kernel_launch(void* const* d_in, const int* in_sizes, int n_in,
                              void* d_out, int out_size, void* d_ws, size_t ws_size,
                              hipStream_t stream)
{
    const float* x  = (const float*)d_in[0];  // [16,64,64,512]
    const float* Wm = (const float*)d_in[1];  // [512,64]
    const float* bv = (const float*)d_in[2];  // [64]
    const float* Cm = (const float*)d_in[3];  // [64,64]

    float* A_g = (float*)d_ws;                        // 65536 f32
    float* sumS_g = A_g + NB * KCL * KCL;             // 1024 f32
    unsigned short* Wt_g = (unsigned short*)(sumS_g + NB * KCL);  // 32768 bf16

    const int nz = NB * KCL * KCL + NB * KCL;         // 66560
    vlad_prep<<<(nz + 255) / 256, 256, 0, stream>>>(Wm, A_g, Wt_g);
    vlad_main<<<NB * NCHUNK, 256, 0, stream>>>(x, Wt_g, bv, A_g, sumS_g);
    vlad_finalize<<<NB, 256, 0, stream>>>(A_g, sumS_g, Cm, (float*)d_out);
}

// Round 5
// 208.708 us; speedup vs baseline: 1.3300x; 1.0939x over previous
//
#include <hip/hip_runtime.h>
#include <hip/hip_bf16.h>

// B=16, H=W=64, Cin=512, K=dim=64
#define NB 16
#define HW 4096
#define CIN 512
#define KCL 64
#define BP 128                 // pixels per block
#define NCHUNK 32              // blocks per batch
#define PSTRIDE 136            // ushort stride for ft/st rows (k-major), 16B-aligned rows

typedef short s16x8 __attribute__((ext_vector_type(8)));
typedef int   i32x4 __attribute__((ext_vector_type(4)));
typedef float f32x4 __attribute__((ext_vector_type(4)));

__device__ __forceinline__ unsigned short f2bf(float f) {
    unsigned u = __builtin_bit_cast(unsigned, f);
    u += 0x7fffu + ((u >> 16) & 1u);   // round-to-nearest-even
    return (unsigned short)(u >> 16);
}

__device__ __forceinline__ unsigned pk2(float lo, float hi) {
    __hip_bfloat162 h = __float22bfloat162_rn(make_float2(lo, hi));  // v_cvt_pk_bf16_f32
    unsigned r;
    __builtin_memcpy(&r, &h, 4);
    return r;
}

// prep: zero A_g+sumS_g + convert/transpose W -> Wt_g bf16 k-major [64][512]
__global__ void vlad_prep(const float* __restrict__ Wm, float* __restrict__ A_g,
                          unsigned short* __restrict__ Wt_g)
{
    const int i = blockIdx.x * 256 + threadIdx.x;
    if (i < NB * KCL * KCL + NB * KCL) A_g[i] = 0.f;   // A_g and sumS contiguous
    if (i < CIN * KCL) {
        const int c = i >> 6;
        const int n = i & 63;
        Wt_g[n * 512 + c] = f2bf(Wm[i]);
    }
}

__global__ __launch_bounds__(256, 4) void vlad_main(
    const float* __restrict__ x, const unsigned short* __restrict__ Wt_g,
    const float* __restrict__ bv, float* __restrict__ A_g,
    float* __restrict__ sumS_g)
{
    __shared__ unsigned short ft[KCL * PSTRIDE];   // F^T: [logit d][pixel p] bf16
    __shared__ unsigned short st[KCL * PSTRIDE];   // S^T: [cluster k][pixel p] bf16

    const int t = threadIdx.x;
    const int b = blockIdx.x >> 5;
    const int chunk = blockIdx.x & 31;
    const int pb = b * HW + chunk * BP;

    const int wid = t >> 6;
    const int lane = t & 63;
    const int col = lane & 15;     // MFMA A-row / B-col / D-col
    const int g = lane >> 4;       // K-slot group
    const int wpix = pb + wid * 32;

    // ---- phase 1: f = x W + b via MFMA, A-frags straight from global ----
    f32x4 acc[2][4];
#pragma unroll
    for (int mt = 0; mt < 2; ++mt)
#pragma unroll
        for (int nt = 0; nt < 4; ++nt) acc[mt][nt] = (f32x4){0.f, 0.f, 0.f, 0.f};

    const float* xr0 = x + (size_t)(wpix + col) * CIN + g * 8;
    const float* xr1 = xr0 + 16 * CIN;
    const unsigned short* wbase = Wt_g + col * 512 + g * 8;

#pragma unroll
    for (int kk = 0; kk < 16; ++kk) {
        const int k0 = kk * 32;
        const float4 u00 = *(const float4*)(xr0 + k0);
        const float4 u01 = *(const float4*)(xr0 + k0 + 4);
        const float4 u10 = *(const float4*)(xr1 + k0);
        const float4 u11 = *(const float4*)(xr1 + k0 + 4);
        s16x8 wf[4];
#pragma unroll
        for (int nt = 0; nt < 4; ++nt)
            wf[nt] = *(const s16x8*)(wbase + nt * (16 * 512) + k0);
        const i32x4 a0i = {(int)pk2(u00.x, u00.y), (int)pk2(u00.z, u00.w),
                           (int)pk2(u01.x, u01.y), (int)pk2(u01.z, u01.w)};
        const i32x4 a1i = {(int)pk2(u10.x, u10.y), (int)pk2(u10.z, u10.w),
                           (int)pk2(u11.x, u11.y), (int)pk2(u11.z, u11.w)};
        const s16x8 a0 = __builtin_bit_cast(s16x8, a0i);
        const s16x8 a1 = __builtin_bit_cast(s16x8, a1i);
#pragma unroll
        for (int nt = 0; nt < 4; ++nt) {
            acc[0][nt] = __builtin_amdgcn_mfma_f32_16x16x32_bf16(a0, wf[nt], acc[0][nt], 0, 0, 0);
            acc[1][nt] = __builtin_amdgcn_mfma_f32_16x16x32_bf16(a1, wf[nt], acc[1][nt], 0, 0, 0);
        }
    }

    // ---- bias + softmax; write F^T,S^T (bf16, k-major); sumS in regs ----
    float bj[4];
#pragma unroll
    for (int nt = 0; nt < 4; ++nt) bj[nt] = bv[nt * 16 + col];
    float ssum[4] = {0.f, 0.f, 0.f, 0.f};

#pragma unroll
    for (int mt = 0; mt < 2; ++mt)
#pragma unroll
        for (int r = 0; r < 4; ++r) {
            float v0 = acc[mt][0][r] + bj[0];
            float v1 = acc[mt][1][r] + bj[1];
            float v2 = acc[mt][2][r] + bj[2];
            float v3 = acc[mt][3][r] + bj[3];
            float m = fmaxf(fmaxf(v0, v1), fmaxf(v2, v3));
            m = fmaxf(m, __shfl_xor(m, 1));
            m = fmaxf(m, __shfl_xor(m, 2));
            m = fmaxf(m, __shfl_xor(m, 4));
            m = fmaxf(m, __shfl_xor(m, 8));
            const float e0 = __expf(v0 - m);
            const float e1 = __expf(v1 - m);
            const float e2 = __expf(v2 - m);
            const float e3 = __expf(v3 - m);
            float lsum = e0 + e1 + e2 + e3;
            lsum += __shfl_xor(lsum, 1);
            lsum += __shfl_xor(lsum, 2);
            lsum += __shfl_xor(lsum, 4);
            lsum += __shfl_xor(lsum, 8);
            const float rl = 1.0f / lsum;
            const float s0 = e0 * rl, s1 = e1 * rl, s2 = e2 * rl, s3 = e3 * rl;
            ssum[0] += s0; ssum[1] += s1; ssum[2] += s2; ssum[3] += s3;
            const int p = wid * 32 + mt * 16 + g * 4 + r;
            ft[(col)      * PSTRIDE + p] = f2bf(v0);
            ft[(col + 16) * PSTRIDE + p] = f2bf(v1);
            ft[(col + 32) * PSTRIDE + p] = f2bf(v2);
            ft[(col + 48) * PSTRIDE + p] = f2bf(v3);
            st[(col)      * PSTRIDE + p] = f2bf(s0);
            st[(col + 16) * PSTRIDE + p] = f2bf(s1);
            st[(col + 32) * PSTRIDE + p] = f2bf(s2);
            st[(col + 48) * PSTRIDE + p] = f2bf(s3);
        }

    // reduce ssum over the 4 K-slot groups (lane bits 4,5) -> per-wave sums
#pragma unroll
    for (int nt = 0; nt < 4; ++nt) {
        ssum[nt] += __shfl_xor(ssum[nt], 16);
        ssum[nt] += __shfl_xor(ssum[nt], 32);
    }
    if (g == 0) {
#pragma unroll
        for (int nt = 0; nt < 4; ++nt)
            atomicAdd(sumS_g + b * KCL + nt * 16 + col, ssum[nt]);
    }
    __syncthreads();

    // ---- phase 2: A[d][k] = sum_p F[p][d] S[p][k] via MFMA (K=128) ----
    f32x4 acc2[4];
#pragma unroll
    for (int nt = 0; nt < 4; ++nt) acc2[nt] = (f32x4){0.f, 0.f, 0.f, 0.f};

    const unsigned short* fta = ft + (wid * 16 + col) * PSTRIDE + g * 8;
#pragma unroll
    for (int kk = 0; kk < 4; ++kk) {
        const s16x8 af = *(const s16x8*)(fta + kk * 32);
#pragma unroll
        for (int nt = 0; nt < 4; ++nt) {
            const s16x8 bf = *(const s16x8*)(st + (nt * 16 + col) * PSTRIDE + kk * 32 + g * 8);
            acc2[nt] = __builtin_amdgcn_mfma_f32_16x16x32_bf16(af, bf, acc2[nt], 0, 0, 0);
        }
    }

    float* Ab = A_g + b * (KCL * KCL);
#pragma unroll
    for (int nt = 0; nt < 4; ++nt)
#pragma unroll
        for (int r = 0; r < 4; ++r)
            atomicAdd(Ab + (wid * 16 + g * 4 + r) * KCL + nt * 16 + col, acc2[nt][r]);
}

__global__ __launch_bounds__(256) void vlad_finalize(
    const float* __restrict__ A_g, const float* __restrict__ sumS_g,
    const float* __restrict__ Cm, float* __restrict__ out)
{
    __shared__ float red[4];
    const int b = blockIdx.x;
    const int t = threadIdx.x;
    const int k = t >> 2;
    const int dg = t & 3;
    const float sS = sumS_g[b * 64 + k];
    float v[16];
    float ssq = 0.f;
#pragma unroll
    for (int i = 0; i < 16; ++i) {
        const int d = dg * 16 + i;
        const float val = A_g[((size_t)b * 64 + d) * 64 + k] + Cm[d * 64 + k] * sS;
        v[i] = val;
        ssq += val * val;
    }
    ssq += __shfl_xor(ssq, 1);
    ssq += __shfl_xor(ssq, 2);
    const float rn = rsqrtf(fmaxf(ssq, 1e-12f));
    float gpart = 0.f;
#pragma unroll
    for (int i = 0; i < 16; ++i) {
        v[i] *= rn;
        gpart += v[i] * v[i];
    }
#pragma unroll
    for (int m = 1; m < 64; m <<= 1) gpart += __shfl_xor(gpart, m);
    if ((t & 63) == 0) red[t >> 6] = gpart;
    __syncthreads();
    const float gsq = red[0] + red[1] + red[2] + red[3];
    const float gr = rsqrtf(fmaxf(gsq, 1e-12f));
    float* o = out + (size_t)b * 4096 + k * 64 + dg * 16;
#pragma unroll
    for (int i = 0; i < 16; ++i) o[i] = v[i] * gr;
}

extern "C" void kernel_launch(void* const* d_in, const int* in_sizes, int n_in,
                              void* d_out, int out_size, void* d_ws, size_t ws_size,
                              hipStream_t stream)
{
    const float* x  = (const float*)d_in[0];  // [16,64,64,512]
    const float* Wm = (const float*)d_in[1];  // [512,64]
    const float* bv = (const float*)d_in[2];  // [64]
    const float* Cm = (const float*)d_in[3];  // [64,64]

    float* A_g = (float*)d_ws;                        // 65536 f32
    float* sumS_g = A_g + NB * KCL * KCL;             // 1024 f32
    unsigned short* Wt_g = (unsigned short*)(sumS_g + NB * KCL);  // 32768 bf16

    const int nz = NB * KCL * KCL + NB * KCL;         // 66560
    vlad_prep<<<(nz + 255) / 256, 256, 0, stream>>>(Wm, A_g, Wt_g);
    vlad_main<<<NB * NCHUNK, 256, 0, stream>>>(x, Wt_g, bv, A_g, sumS_g);
    vlad_finalize<<<NB, 256, 0, stream>>>(A_g, sumS_g, Cm, (float*)d_out);
}